// Round 10
// baseline (135.396 us; speedup 1.0000x reference)
//
#include <hip/hip_runtime.h>
#include <math.h>

namespace {

constexpr int kRows = 4096;
constexpr int kNF   = 65;
constexpr int kNE   = 256;
constexpr int kNH   = 8;
constexpr int kNC   = 64;                  // kNF - 1 fields used
constexpr int kXRow = kNF * kNE;           // 16640 floats per x row
constexpr int kORow = (kNF + kNH) * kNE;   // 18688 floats per out row

typedef float vf4 __attribute__((ext_vector_type(4)));  // NT-store-compatible

__device__ __forceinline__ void nt_store4(const float4& v, float4* dst) {
  vf4 t = {v.x, v.y, v.z, v.w};
  __builtin_nontemporal_store(t, reinterpret_cast<vf4*>(dst));
}

// w2[t] = sum_k bw[t*256+k] * query[(t>>5)*256+k].  32 blocks x 256 threads.
__global__ __launch_bounds__(256) void w2_precompute(
    const float* __restrict__ bw, const float* __restrict__ query,
    float* __restrict__ w2) {
  const int o = threadIdx.x >> 5;          // 0..7: which of this block's outputs
  const int l = threadIdx.x & 31;          // 32 lanes per output
  const int t = blockIdx.x * 8 + o;
  const int h = t >> 5;
  const float4* __restrict__ bp =
      reinterpret_cast<const float4*>(bw + (size_t)t * 256 + l * 8);
  const float4* __restrict__ qp =
      reinterpret_cast<const float4*>(query + (size_t)h * 256 + l * 8);
  const float4 b0 = bp[0], b1 = bp[1];
  const float4 q0 = qp[0], q1 = qp[1];
  float acc = b0.x * q0.x + b0.y * q0.y + b0.z * q0.z + b0.w * q0.w
            + b1.x * q1.x + b1.y * q1.y + b1.z * q1.z + b1.w * q1.w;
  acc += __shfl_xor(acc, 1);
  acc += __shfl_xor(acc, 2);
  acc += __shfl_xor(acc, 4);
  acc += __shfl_xor(acc, 8);
  acc += __shfl_xor(acc, 16);
  if (l == 0) w2[t] = acc;
}

// One block = one row, 256 threads = 4 waves -> 8 blocks/CU (thread ceiling),
// doubling independent rows in flight vs the 512-thread version (round 9:
// occupancy 55%, BW 4.1 TB/s, convoy-limited). Wave wv owns keys
// c = wv*16..wv*16+15, processed in 2 batches of 8 (bounds in-flight regs).
// att_t overlays the part buffer (dead after entmax's X-load; barrier makes
// the overlay safe) -> LDS ~18.4 KB. Phase C re-loads keys from global
// explicitly (the allocator's preferred remat; rows are L3-hot from phase A).
// No min-waves hints (rounds 3-5: min-waves W caps allocator at 256/W VGPRs
// and spills). NT stores for all out writes (round 8: keeps x L3-resident).
__global__ __launch_bounds__(256) void fused_row(
    const float* __restrict__ x, const float* __restrict__ w2g,
    const float* __restrict__ vals, float* __restrict__ out) {
  __shared__ float cw[kNC * kNH];         // [c][h], 2 KB
  __shared__ float4 part[4 * 4 * 64];     // [slot][head4][equad], 16 KB (x2 passes)
  float* att_t = reinterpret_cast<float*>(part);  // overlay: 64*9*4 = 2304 B

  const int tid  = threadIdx.x;
  const int wv   = tid >> 6;
  const int lane = tid & 63;
  const int r    = blockIdx.x;

  const float* __restrict__ xrow = x + (size_t)r * kXRow;
  float* __restrict__ orow       = out + (size_t)r * kORow;
  const float4* __restrict__ x4  = reinterpret_cast<const float4*>(xrow);
  float4* __restrict__ o4        = reinterpret_cast<float4*>(orow);

  // ---- phase A: 2 batches of 8 fields; per batch: issue 8 loads, then
  //      copy -> out (NT) + att dot + 3-level shfl reduce over lane&7.
  //      Lane's w2 quad: head h = lane>>3, dims 4*(lane&7)..+3.
  const float4 wq = reinterpret_cast<const float4*>(w2g)[lane];
  float4 v0;
  if (wv == 0) v0 = x4[lane];           // field 0: copy only (not a key)
#pragma unroll
  for (int b = 0; b < 2; ++b) {
    float4 buf[8];
#pragma unroll
    for (int j = 0; j < 8; ++j) {
      buf[j] = x4[(wv * 16 + b * 8 + j + 1) * 64 + lane];
    }
    if (b == 0 && wv == 0) nt_store4(v0, &o4[lane]);
#pragma unroll
    for (int j = 0; j < 8; ++j) {
      const int c = wv * 16 + b * 8 + j;   // key index; field f = c+1
      const float4 v = buf[j];
      nt_store4(v, &o4[(c + 1) * 64 + lane]);
      float p = v.x * wq.x + v.y * wq.y + v.z * wq.z + v.w * wq.w;
      p += __shfl_xor(p, 1);
      p += __shfl_xor(p, 2);
      p += __shfl_xor(p, 4);
      if ((lane & 7) == 0) att_t[c * 9 + (lane >> 3)] = p * 0.03125f;
    }
  }
  __syncthreads();

  // ---- entmax-1.5 via Newton on f(tau) = sum clip(X-tau)^2 - 1 (convex,
  //      decreasing, |f'| >= 2 near root; tau0 = mx-1 has f >= 0; monotone
  //      convergence to the same fp32 fixed point as the reference's 50-iter
  //      bisection — verified round 9, absmax unchanged). Run redundantly by
  //      all 4 waves (identical inputs/ops -> bitwise-identical; cw writes
  //      are a benign identical-value race; each wave reads back only its own
  //      writes -> no barrier before phase C). lane = h*8+kk, 8 c's/lane.
  {
    const int h  = lane >> 3;
    const int kk = lane & 7;
    float X[8];
#pragma unroll
    for (int j = 0; j < 8; ++j) X[j] = att_t[(kk * 8 + j) * 9 + h];
    __syncthreads();   // att_t now dead -> part overlay may be written

    float mx = X[0];
#pragma unroll
    for (int j = 1; j < 8; ++j) mx = fmaxf(mx, X[j]);
    mx = fmaxf(mx, __shfl_xor(mx, 1));
    mx = fmaxf(mx, __shfl_xor(mx, 2));
    mx = fmaxf(mx, __shfl_xor(mx, 4));

    float tau = mx - 1.0f;            // f(tau0) >= 0 (largest clip term = 1)
    for (int it = 0; it < 16; ++it) {
      float s2 = 0.f, s1 = 0.f;
#pragma unroll
      for (int j = 0; j < 8; ++j) {
        const float t = fmaxf(X[j] - tau, 0.f);
        s2 += t * t;
        s1 += t;
      }
      s2 += __shfl_xor(s2, 1); s1 += __shfl_xor(s1, 1);
      s2 += __shfl_xor(s2, 2); s1 += __shfl_xor(s1, 2);
      s2 += __shfl_xor(s2, 4); s1 += __shfl_xor(s1, 4);
      const float delta = (s2 - 1.0f) / (2.0f * fmaxf(s1, 1e-30f));
      const float ntau = tau + delta;
      if (__all(ntau == tau)) break;   // fp32 fixed point reached
      tau = ntau;
    }

    float s = 0.f;
    float p[8];
#pragma unroll
    for (int j = 0; j < 8; ++j) {
      const float t = fmaxf(X[j] - tau, 0.f);
      p[j] = t * t;
      s += p[j];
    }
    s += __shfl_xor(s, 1);
    s += __shfl_xor(s, 2);
    s += __shfl_xor(s, 4);
    const float inv = 1.0f / s;
    const float* __restrict__ vrow = vals + h * kNC + kk * 8;   // L2-hot
#pragma unroll
    for (int j = 0; j < 8; ++j) {
      cw[(kk * 8 + j) * kNH + h] = p[j] * inv * vrow[j];
    }
  }
  // no barrier: each wave reads back only cw values it wrote itself.

  // ---- phase C: 2 passes of 4 heads. Per pass: per-wave partials over its
  //      16 keys (explicit global re-loads, L3-hot; 2 batches of 8) ->
  //      part[wv] -> barrier -> 256-thread float4 sum of 4 slots + __expf +
  //      NT store. cw4[c*2+hh] = heads 4hh..4hh+3 of key c (broadcast read).
  const float4* __restrict__ cw4 = reinterpret_cast<const float4*>(cw);
#pragma unroll
  for (int hh = 0; hh < 2; ++hh) {
    float4 a0 = make_float4(0.f, 0.f, 0.f, 0.f);
    float4 a1 = make_float4(0.f, 0.f, 0.f, 0.f);
    float4 a2 = make_float4(0.f, 0.f, 0.f, 0.f);
    float4 a3 = make_float4(0.f, 0.f, 0.f, 0.f);
#pragma unroll
    for (int b = 0; b < 2; ++b) {
      float4 kb[8];
#pragma unroll
      for (int j = 0; j < 8; ++j) {
        kb[j] = x4[(wv * 16 + b * 8 + j + 1) * 64 + lane];
      }
#pragma unroll
      for (int j = 0; j < 8; ++j) {
        const float4 kv = kb[j];
        const float4 ca = cw4[(wv * 16 + b * 8 + j) * 2 + hh];
        a0.x += ca.x * kv.x; a0.y += ca.x * kv.y; a0.z += ca.x * kv.z; a0.w += ca.x * kv.w;
        a1.x += ca.y * kv.x; a1.y += ca.y * kv.y; a1.z += ca.y * kv.z; a1.w += ca.y * kv.w;
        a2.x += ca.z * kv.x; a2.y += ca.z * kv.y; a2.z += ca.z * kv.z; a2.w += ca.z * kv.w;
        a3.x += ca.w * kv.x; a3.y += ca.w * kv.y; a3.z += ca.w * kv.z; a3.w += ca.w * kv.w;
      }
    }
    part[wv * 256 + 0 * 64 + lane] = a0;   // lane-consecutive b128, conflict-free
    part[wv * 256 + 1 * 64 + lane] = a1;
    part[wv * 256 + 2 * 64 + lane] = a2;
    part[wv * 256 + 3 * 64 + lane] = a3;
    __syncthreads();
    {
      // tid covers this pass's 1024 outputs as float4: h' = tid>>6, e-quad = tid&63
      float4 s = part[tid];
#pragma unroll
      for (int sl = 1; sl < 4; ++sl) {
        const float4 t = part[sl * 256 + tid];
        s.x += t.x; s.y += t.y; s.z += t.z; s.w += t.w;
      }
      float4 e;
      e.x = __expf(s.x); e.y = __expf(s.y); e.z = __expf(s.z); e.w = __expf(s.w);
      nt_store4(e, &reinterpret_cast<float4*>(orow + kXRow + hh * 1024)[tid]);
    }
    if (hh == 0) __syncthreads();          // protect part reuse by pass 2
  }
}

}  // namespace

extern "C" void kernel_launch(void* const* d_in, const int* in_sizes, int n_in,
                              void* d_out, int out_size, void* d_ws, size_t ws_size,
                              hipStream_t stream) {
  const float* x     = reinterpret_cast<const float*>(d_in[0]);
  const float* bw    = reinterpret_cast<const float*>(d_in[1]);
  const float* query = reinterpret_cast<const float*>(d_in[2]);
  const float* vals  = reinterpret_cast<const float*>(d_in[3]);
  float* out = reinterpret_cast<float*>(d_out);
  float* w2  = reinterpret_cast<float*>(d_ws);   // 256 floats of scratch

  hipLaunchKernelGGL(w2_precompute, dim3(32), dim3(256), 0, stream, bw, query, w2);
  hipLaunchKernelGGL(fused_row, dim3(kRows), dim3(256), 0, stream, x, w2, vals, out);
}

// Round 11
// 133.242 us; speedup vs baseline: 1.0162x; 1.0162x over previous
//
#include <hip/hip_runtime.h>
#include <math.h>

namespace {

constexpr int kRows = 4096;
constexpr int kNF   = 65;
constexpr int kNE   = 256;
constexpr int kNH   = 8;
constexpr int kNC   = 64;                  // kNF - 1 fields used
constexpr int kXRow = kNF * kNE;           // 16640 floats per x row
constexpr int kORow = (kNF + kNH) * kNE;   // 18688 floats per out row

typedef float vf4 __attribute__((ext_vector_type(4)));  // NT-store-compatible

__device__ __forceinline__ void nt_store4(const float4& v, float4* dst) {
  vf4 t = {v.x, v.y, v.z, v.w};
  __builtin_nontemporal_store(t, reinterpret_cast<vf4*>(dst));
}

// w2[t] = sum_k bw[t*256+k] * query[(t>>5)*256+k].  32 blocks x 256 threads.
__global__ __launch_bounds__(256) void w2_precompute(
    const float* __restrict__ bw, const float* __restrict__ query,
    float* __restrict__ w2) {
  const int o = threadIdx.x >> 5;          // 0..7: which of this block's outputs
  const int l = threadIdx.x & 31;          // 32 lanes per output
  const int t = blockIdx.x * 8 + o;
  const int h = t >> 5;
  const float4* __restrict__ bp =
      reinterpret_cast<const float4*>(bw + (size_t)t * 256 + l * 8);
  const float4* __restrict__ qp =
      reinterpret_cast<const float4*>(query + (size_t)h * 256 + l * 8);
  const float4 b0 = bp[0], b1 = bp[1];
  const float4 q0 = qp[0], q1 = qp[1];
  float acc = b0.x * q0.x + b0.y * q0.y + b0.z * q0.z + b0.w * q0.w
            + b1.x * q1.x + b1.y * q1.y + b1.z * q1.z + b1.w * q1.w;
  acc += __shfl_xor(acc, 1);
  acc += __shfl_xor(acc, 2);
  acc += __shfl_xor(acc, 4);
  acc += __shfl_xor(acc, 8);
  acc += __shfl_xor(acc, 16);
  if (l == 0) w2[t] = acc;
}

// PERSISTENT blocks: grid 1024 (= 4 blocks/CU residency), each block handles
// 4 consecutive rows. Round-10 lesson: one-shot 4096-block launch creates
// generation convoys — each CU's 4 blocks start aligned, do phase A (HBM
// rush) then B+C (HBM idle) in lockstep, retire together. Rolling g->g+1
// inside the block lets the 4 resident blocks' phases drift and stay
// decorrelated, keeping the HBM pipe fed. Per row: 512 threads = 8 waves;
// wave wv owns keys c=8wv..8wv+7 (kreg[8]); Newton entmax; 2-pass phase C.
// No min-waves hints (rounds 3-5: min-waves W caps allocator at 256/W VGPRs
// and spills). NT stores for out (round 8: keeps x L3-resident, FETCH 133MB).
//
// g-loop barrier safety: the next write of each shared buffer is ordered
// behind a block-wide barrier that postdates all prior-row reads of it:
//   att_t(g+1) written in phase A, read at entmax after A-barrier(g+1);
//   laggards still in g's phase-C reduce touch only part/cw, not att_t.
//   cw(g+1) written at entmax, which is after A-barrier(g+1) — that barrier
//   requires every wave to have finished g entirely (incl. its cw4 reads).
//   part(g+1) first written at hh0 after A-barrier(g+1) — same argument
//   covers g's hh1 partf reads (which precede that barrier per wave).
__global__ __launch_bounds__(512) void fused_row(
    const float* __restrict__ x, const float* __restrict__ w2g,
    const float* __restrict__ vals, float* __restrict__ out) {
  __shared__ float att_t[kNC * 9];        // [c][h] stride 9: conflict-free gather
  __shared__ float cw[kNC * kNH];         // [c][h], 2 KB
  __shared__ float4 part[8 * 4 * 64];     // [slot][head4][equad], 32 KB (x2 passes)

  const int tid  = threadIdx.x;
  const int wv   = tid >> 6;
  const int lane = tid & 63;

  // Lane's w2 quad: head h = lane>>3, dims 4*(lane&7)..+3 (hoisted over rows).
  const float4 wq = reinterpret_cast<const float4*>(w2g)[lane];
  const float4* __restrict__ cw4 = reinterpret_cast<const float4*>(cw);
  const float* partf             = reinterpret_cast<const float*>(part);

#pragma unroll 1
  for (int g = 0; g < 4; ++g) {
    const int r = blockIdx.x * 4 + g;
    const float* __restrict__ xrow = x + (size_t)r * kXRow;
    float* __restrict__ orow       = out + (size_t)r * kORow;
    const float4* __restrict__ x4  = reinterpret_cast<const float4*>(xrow);
    float4* __restrict__ o4        = reinterpret_cast<float4*>(orow);

    // ---- phase A: issue ALL loads first (9 outstanding vmem per wave), then
    //      copy -> out (NT) + att dot + 3-level shfl reduce over lane&7.
    float4 kreg[8];
    float4 v0;
    if (wv == 0) v0 = x4[lane];           // field 0: copy only (not a key)
#pragma unroll
    for (int j = 0; j < 8; ++j) {
      kreg[j] = x4[(wv * 8 + j + 1) * 64 + lane];
    }
    if (wv == 0) nt_store4(v0, &o4[lane]);
#pragma unroll
    for (int j = 0; j < 8; ++j) {
      const int c = wv * 8 + j;           // key index; field f = c+1
      const float4 v = kreg[j];
      nt_store4(v, &o4[(c + 1) * 64 + lane]);
      float p = v.x * wq.x + v.y * wq.y + v.z * wq.z + v.w * wq.w;
      p += __shfl_xor(p, 1);
      p += __shfl_xor(p, 2);
      p += __shfl_xor(p, 4);
      if ((lane & 7) == 0) att_t[c * 9 + (lane >> 3)] = p * 0.03125f;
    }
    __syncthreads();

    // ---- entmax-1.5 via Newton on f(tau) = sum clip(X-tau)^2 - 1 (convex,
    //      decreasing, |f'| >= 2 near root; tau0 = mx-1 has f >= 0; monotone
    //      convergence to the same fp32 fixed point as the reference's
    //      50-iter bisection — verified rounds 9-10, absmax unchanged).
    //      Run redundantly by all 8 waves (bitwise-identical; cw writes are a
    //      benign identical-value race; each wave reads back only its own
    //      writes -> no barrier before phase C). lane = h*8+kk, 8 c's/lane.
    {
      const int h  = lane >> 3;
      const int kk = lane & 7;
      float X[8];
#pragma unroll
      for (int j = 0; j < 8; ++j) X[j] = att_t[(kk * 8 + j) * 9 + h];

      float mx = X[0];
#pragma unroll
      for (int j = 1; j < 8; ++j) mx = fmaxf(mx, X[j]);
      mx = fmaxf(mx, __shfl_xor(mx, 1));
      mx = fmaxf(mx, __shfl_xor(mx, 2));
      mx = fmaxf(mx, __shfl_xor(mx, 4));

      float tau = mx - 1.0f;            // f(tau0) >= 0 (largest clip term = 1)
      for (int it = 0; it < 16; ++it) {
        float s2 = 0.f, s1 = 0.f;
#pragma unroll
        for (int j = 0; j < 8; ++j) {
          const float t = fmaxf(X[j] - tau, 0.f);
          s2 += t * t;
          s1 += t;
        }
        s2 += __shfl_xor(s2, 1); s1 += __shfl_xor(s1, 1);
        s2 += __shfl_xor(s2, 2); s1 += __shfl_xor(s1, 2);
        s2 += __shfl_xor(s2, 4); s1 += __shfl_xor(s1, 4);
        const float delta = (s2 - 1.0f) / (2.0f * fmaxf(s1, 1e-30f));
        const float ntau = tau + delta;
        if (__all(ntau == tau)) break;   // fp32 fixed point reached
        tau = ntau;
      }

      float s = 0.f;
      float p[8];
#pragma unroll
      for (int j = 0; j < 8; ++j) {
        const float t = fmaxf(X[j] - tau, 0.f);
        p[j] = t * t;
        s += p[j];
      }
      s += __shfl_xor(s, 1);
      s += __shfl_xor(s, 2);
      s += __shfl_xor(s, 4);
      const float inv = 1.0f / s;
      const float* __restrict__ vrow = vals + h * kNC + kk * 8;   // L2-hot
#pragma unroll
      for (int j = 0; j < 8; ++j) {
        cw[(kk * 8 + j) * kNH + h] = p[j] * inv * vrow[j];
      }
    }
    // no barrier: each wave reads back only cw values it wrote itself.

    // ---- phase C: 2 passes of 4 heads through the reused 32 KB part buffer.
    //      Per pass: per-wave partials (keys from kreg; the allocator remats
    //      them as L3-hot global reloads at VGPR ~40 — measured round 9, no
    //      scratch) -> part[wv] -> barrier -> 512-thread scalar sum of 8
    //      slots + __expf + NT store.
#pragma unroll
    for (int hh = 0; hh < 2; ++hh) {
      float4 a0 = make_float4(0.f, 0.f, 0.f, 0.f);
      float4 a1 = make_float4(0.f, 0.f, 0.f, 0.f);
      float4 a2 = make_float4(0.f, 0.f, 0.f, 0.f);
      float4 a3 = make_float4(0.f, 0.f, 0.f, 0.f);
#pragma unroll
      for (int j = 0; j < 8; ++j) {
        const float4 kv = kreg[j];
        const float4 ca = cw4[(wv * 8 + j) * 2 + hh];  // broadcast: heads 4hh..+3
        a0.x += ca.x * kv.x; a0.y += ca.x * kv.y; a0.z += ca.x * kv.z; a0.w += ca.x * kv.w;
        a1.x += ca.y * kv.x; a1.y += ca.y * kv.y; a1.z += ca.y * kv.z; a1.w += ca.y * kv.w;
        a2.x += ca.z * kv.x; a2.y += ca.z * kv.y; a2.z += ca.z * kv.z; a2.w += ca.z * kv.w;
        a3.x += ca.w * kv.x; a3.y += ca.w * kv.y; a3.z += ca.w * kv.z; a3.w += ca.w * kv.w;
      }
      part[wv * 256 + 0 * 64 + lane] = a0;   // lane-consecutive b128, conflict-free
      part[wv * 256 + 1 * 64 + lane] = a1;
      part[wv * 256 + 2 * 64 + lane] = a2;
      part[wv * 256 + 3 * 64 + lane] = a3;
      __syncthreads();
#pragma unroll
      for (int oo = 0; oo < 2; ++oo) {
        const int o = oo * 512 + tid;        // head4*256 + e within this pass
        float s = partf[o];
#pragma unroll
        for (int sl = 1; sl < 8; ++sl) s += partf[sl * 1024 + o];
        __builtin_nontemporal_store(__expf(s), &orow[kXRow + hh * 1024 + o]);
      }
      if (hh == 0) __syncthreads();          // protect part reuse by pass 2
      // after hh==1: next write of part is g+1's hh0, which sits behind
      // g+1's phase-A barrier -> laggards' partf reads here are safe.
    }
  }
}

}  // namespace

extern "C" void kernel_launch(void* const* d_in, const int* in_sizes, int n_in,
                              void* d_out, int out_size, void* d_ws, size_t ws_size,
                              hipStream_t stream) {
  const float* x     = reinterpret_cast<const float*>(d_in[0]);
  const float* bw    = reinterpret_cast<const float*>(d_in[1]);
  const float* query = reinterpret_cast<const float*>(d_in[2]);
  const float* vals  = reinterpret_cast<const float*>(d_in[3]);
  float* out = reinterpret_cast<float*>(d_out);
  float* w2  = reinterpret_cast<float*>(d_ws);   // 256 floats of scratch

  hipLaunchKernelGGL(w2_precompute, dim3(32), dim3(256), 0, stream, bw, query, w2);
  hipLaunchKernelGGL(fused_row, dim3(kRows / 4), dim3(512), 0, stream, x, w2, vals, out);
}

// Round 12
// 98.670 us; speedup vs baseline: 1.3722x; 1.3504x over previous
//
#include <hip/hip_runtime.h>
#include <math.h>

namespace {

constexpr int kRows = 4096;
constexpr int kNF   = 65;
constexpr int kNE   = 256;
constexpr int kNH   = 8;
constexpr int kNC   = 64;                  // kNF - 1 fields used
constexpr int kXRow = kNF * kNE;           // 16640 floats per x row
constexpr int kORow = (kNF + kNH) * kNE;   // 18688 floats per out row

typedef float vf4 __attribute__((ext_vector_type(4)));  // NT-store-compatible

__device__ __forceinline__ void nt_store4(const float4& v, float4* dst) {
  vf4 t = {v.x, v.y, v.z, v.w};
  __builtin_nontemporal_store(t, reinterpret_cast<vf4*>(dst));
}

// w2[t] = sum_k bw[t*256+k] * query[(t>>5)*256+k].  32 blocks x 256 threads.
__global__ __launch_bounds__(256) void w2_precompute(
    const float* __restrict__ bw, const float* __restrict__ query,
    float* __restrict__ w2) {
  const int o = threadIdx.x >> 5;          // 0..7: which of this block's outputs
  const int l = threadIdx.x & 31;          // 32 lanes per output
  const int t = blockIdx.x * 8 + o;
  const int h = t >> 5;
  const float4* __restrict__ bp =
      reinterpret_cast<const float4*>(bw + (size_t)t * 256 + l * 8);
  const float4* __restrict__ qp =
      reinterpret_cast<const float4*>(query + (size_t)h * 256 + l * 8);
  const float4 b0 = bp[0], b1 = bp[1];
  const float4 q0 = qp[0], q1 = qp[1];
  float acc = b0.x * q0.x + b0.y * q0.y + b0.z * q0.z + b0.w * q0.w
            + b1.x * q1.x + b1.y * q1.y + b1.z * q1.z + b1.w * q1.w;
  acc += __shfl_xor(acc, 1);
  acc += __shfl_xor(acc, 2);
  acc += __shfl_xor(acc, 4);
  acc += __shfl_xor(acc, 8);
  acc += __shfl_xor(acc, 16);
  if (l == 0) w2[t] = acc;
}

// One block = one row, 512 threads = 8 waves; wave wv owns keys c=8wv..8wv+7
// (kreg[8] = 32 VGPRs). Round-9 config (107.6 us) + ONE isolated change:
// entmax runs in wave 0 ONLY (+1 barrier). Rationale: the all-wave redundant
// entmax costs ~25% of total dynamic instructions (8x ~230 VALU + ~50 shfl
// per thread) on the VALU and LDS pipes; a single-wave serial section costs
// only ~0.5 us latency, absorbed by the 3 other resident blocks per CU.
// Persistent blocks (round 11) and 256-thr blocks (round 10) both regressed —
// one-shot 512-thr blocks with scheduler backfill is the best structure found.
// No min-waves hints (rounds 3-5: min-waves W caps allocator at 256/W VGPRs
// and spills). NT stores for all out writes (round 8: x stays L3-resident).
__global__ __launch_bounds__(512) void fused_row(
    const float* __restrict__ x, const float* __restrict__ w2g,
    const float* __restrict__ vals, float* __restrict__ out) {
  __shared__ float att_t[kNC * 9];        // [c][h] stride 9: conflict-free gather
  __shared__ float cw[kNC * kNH];         // [c][h], 2 KB
  __shared__ float4 part[8 * 4 * 64];     // [slot][head4][equad], 32 KB (x2 passes)

  const int tid  = threadIdx.x;
  const int wv   = tid >> 6;
  const int lane = tid & 63;
  const int r    = blockIdx.x;

  const float* __restrict__ xrow = x + (size_t)r * kXRow;
  float* __restrict__ orow       = out + (size_t)r * kORow;
  const float4* __restrict__ x4  = reinterpret_cast<const float4*>(xrow);
  float4* __restrict__ o4        = reinterpret_cast<float4*>(orow);

  // ---- phase A: issue ALL loads first (9 outstanding vmem per wave), then
  //      copy -> out (NT) + att dot + 3-level shfl reduce over lane&7.
  //      Lane's w2 quad: head h = lane>>3, dims 4*(lane&7)..+3.
  float4 kreg[8];
  const float4 wq = reinterpret_cast<const float4*>(w2g)[lane];
  float4 v0;
  if (wv == 0) v0 = x4[lane];           // field 0: copy only (not a key)
#pragma unroll
  for (int j = 0; j < 8; ++j) {
    kreg[j] = x4[(wv * 8 + j + 1) * 64 + lane];
  }
  if (wv == 0) nt_store4(v0, &o4[lane]);
#pragma unroll
  for (int j = 0; j < 8; ++j) {
    const int c = wv * 8 + j;           // key index; field f = c+1
    const float4 v = kreg[j];
    nt_store4(v, &o4[(c + 1) * 64 + lane]);
    float p = v.x * wq.x + v.y * wq.y + v.z * wq.z + v.w * wq.w;
    p += __shfl_xor(p, 1);
    p += __shfl_xor(p, 2);
    p += __shfl_xor(p, 4);
    if ((lane & 7) == 0) att_t[c * 9 + (lane >> 3)] = p * 0.03125f;
  }
  __syncthreads();

  // ---- entmax-1.5 via Newton on f(tau) = sum clip(X-tau)^2 - 1 (convex,
  //      decreasing, |f'| >= 2 near root; tau0 = mx-1 has f >= 0; monotone
  //      convergence to the same fp32 fixed point as the reference's 50-iter
  //      bisection — verified rounds 9-11, absmax unchanged). WAVE 0 ONLY:
  //      lane = h*8+kk, 8 c's per lane; cw published via the barrier below.
  if (wv == 0) {
    const int h  = lane >> 3;
    const int kk = lane & 7;
    float X[8];
#pragma unroll
    for (int j = 0; j < 8; ++j) X[j] = att_t[(kk * 8 + j) * 9 + h];

    float mx = X[0];
#pragma unroll
    for (int j = 1; j < 8; ++j) mx = fmaxf(mx, X[j]);
    mx = fmaxf(mx, __shfl_xor(mx, 1));
    mx = fmaxf(mx, __shfl_xor(mx, 2));
    mx = fmaxf(mx, __shfl_xor(mx, 4));

    float tau = mx - 1.0f;            // f(tau0) >= 0 (largest clip term = 1)
    for (int it = 0; it < 16; ++it) {
      float s2 = 0.f, s1 = 0.f;
#pragma unroll
      for (int j = 0; j < 8; ++j) {
        const float t = fmaxf(X[j] - tau, 0.f);
        s2 += t * t;
        s1 += t;
      }
      s2 += __shfl_xor(s2, 1); s1 += __shfl_xor(s1, 1);
      s2 += __shfl_xor(s2, 2); s1 += __shfl_xor(s1, 2);
      s2 += __shfl_xor(s2, 4); s1 += __shfl_xor(s1, 4);
      const float delta = (s2 - 1.0f) / (2.0f * fmaxf(s1, 1e-30f));
      const float ntau = tau + delta;
      if (__all(ntau == tau)) break;   // fp32 fixed point reached
      tau = ntau;
    }

    float s = 0.f;
    float p[8];
#pragma unroll
    for (int j = 0; j < 8; ++j) {
      const float t = fmaxf(X[j] - tau, 0.f);
      p[j] = t * t;
      s += p[j];
    }
    s += __shfl_xor(s, 1);
    s += __shfl_xor(s, 2);
    s += __shfl_xor(s, 4);
    const float inv = 1.0f / s;
    const float* __restrict__ vrow = vals + h * kNC + kk * 8;   // L2-hot
#pragma unroll
    for (int j = 0; j < 8; ++j) {
      cw[(kk * 8 + j) * kNH + h] = p[j] * inv * vrow[j];
    }
  }
  __syncthreads();   // publish cw (wave 0) to all waves

  // ---- phase C: 2 passes of 4 heads through the reused 32 KB part buffer.
  //      Per pass: per-wave partials (keys from kreg; the allocator remats
  //      them as L3-hot global reloads at VGPR ~40 — measured round 9, no
  //      scratch) -> part[wv] -> barrier -> 512-thread scalar sum of 8 slots
  //      + __expf + NT store. cw4[c*2+hh] = heads 4hh..4hh+3 (broadcast).
  const float4* __restrict__ cw4 = reinterpret_cast<const float4*>(cw);
  const float* partf             = reinterpret_cast<const float*>(part);
#pragma unroll
  for (int hh = 0; hh < 2; ++hh) {
    float4 a0 = make_float4(0.f, 0.f, 0.f, 0.f);
    float4 a1 = make_float4(0.f, 0.f, 0.f, 0.f);
    float4 a2 = make_float4(0.f, 0.f, 0.f, 0.f);
    float4 a3 = make_float4(0.f, 0.f, 0.f, 0.f);
#pragma unroll
    for (int j = 0; j < 8; ++j) {
      const float4 kv = kreg[j];
      const float4 ca = cw4[(wv * 8 + j) * 2 + hh];
      a0.x += ca.x * kv.x; a0.y += ca.x * kv.y; a0.z += ca.x * kv.z; a0.w += ca.x * kv.w;
      a1.x += ca.y * kv.x; a1.y += ca.y * kv.y; a1.z += ca.y * kv.z; a1.w += ca.y * kv.w;
      a2.x += ca.z * kv.x; a2.y += ca.z * kv.y; a2.z += ca.z * kv.z; a2.w += ca.z * kv.w;
      a3.x += ca.w * kv.x; a3.y += ca.w * kv.y; a3.z += ca.w * kv.z; a3.w += ca.w * kv.w;
    }
    part[wv * 256 + 0 * 64 + lane] = a0;   // lane-consecutive b128, conflict-free
    part[wv * 256 + 1 * 64 + lane] = a1;
    part[wv * 256 + 2 * 64 + lane] = a2;
    part[wv * 256 + 3 * 64 + lane] = a3;
    __syncthreads();
#pragma unroll
    for (int oo = 0; oo < 2; ++oo) {
      const int o = oo * 512 + tid;        // o = head4*256 + e within this pass
      float s = partf[o];
#pragma unroll
      for (int sl = 1; sl < 8; ++sl) s += partf[sl * 1024 + o];
      __builtin_nontemporal_store(__expf(s), &orow[kXRow + hh * 1024 + o]);
    }
    if (hh == 0) __syncthreads();          // protect part reuse by pass 2
  }
}

}  // namespace

extern "C" void kernel_launch(void* const* d_in, const int* in_sizes, int n_in,
                              void* d_out, int out_size, void* d_ws, size_t ws_size,
                              hipStream_t stream) {
  const float* x     = reinterpret_cast<const float*>(d_in[0]);
  const float* bw    = reinterpret_cast<const float*>(d_in[1]);
  const float* query = reinterpret_cast<const float*>(d_in[2]);
  const float* vals  = reinterpret_cast<const float*>(d_in[3]);
  float* out = reinterpret_cast<float*>(d_out);
  float* w2  = reinterpret_cast<float*>(d_ws);   // 256 floats of scratch

  hipLaunchKernelGGL(w2_precompute, dim3(32), dim3(256), 0, stream, bw, query, w2);
  hipLaunchKernelGGL(fused_row, dim3(kRows), dim3(512), 0, stream, x, w2, vals, out);
}